// Round 2
// baseline (21267.250 us; speedup 1.0000x reference)
//
#include <hip/hip_runtime.h>
#include <hip/hip_bf16.h>
#include <hip/hip_cooperative_groups.h>
#include <stdint.h>

namespace cg = cooperative_groups;

// Problem constants (fixed by the reference): B=64, L=4, H=1024, T=128.
#define NB   64
#define NH   1024
#define NL   4
#define NT   128

using bf16x8 = __attribute__((ext_vector_type(8))) short;  // 8 bf16 in 4 VGPRs
using f32x4  = __attribute__((ext_vector_type(4))) float;

// Split fp32 v into hi+lo bf16 (RNE). v ~= hi + lo with residual ~2^-17 * |v|.
__device__ __forceinline__ void split_bf16(float v, unsigned short& hi, unsigned short& lo) {
    unsigned u = __float_as_uint(v);
    unsigned short h = (unsigned short)((u + 0x7FFFu + ((u >> 16) & 1u)) >> 16);
    float hf = __uint_as_float((unsigned)h << 16);
    float r  = v - hf;
    unsigned ur = __float_as_uint(r);
    unsigned short l = (unsigned short)((ur + 0x7FFFu + ((ur >> 16) & 1u)) >> 16);
    hi = h; lo = l;
}

// A-swizzle for a (64 x 1024) activation: element (m,k) at
// ((k>>5)*4 + (m>>4))*512 + ((m&15) + ((k>>3)&3)*16)*8 + (k&7).
__device__ __forceinline__ size_t aswz(int m, int k) {
    return ((size_t)((k >> 5) * 4 + (m >> 4)) * 64 + ((m & 15) + ((k >> 3) & 3) * 16)) * 8
           + (k & 7);
}

#define HOFF(p, l) (((size_t)(p) * 4 + (l)) * 65536)

// ---------------------------------------------------------------------------
// prep_w: fp32 W_ih/W_hh -> swizzled hi/lo bf16 B-fragment tiles (verified R1).
// ---------------------------------------------------------------------------
__global__ __launch_bounds__(256)
void prep_w(const float* __restrict__ Wih, const float* __restrict__ Whh,
            unsigned short* __restrict__ Whi, unsigned short* __restrict__ Wlo)
{
    int gid = blockIdx.x * 256 + threadIdx.x;      // (l, kc, nt, L)
    int L  = gid & 63;
    int nt = (gid >> 6) & 255;
    int kc = (gid >> 14) & 63;
    int l  = gid >> 20;                            // 0..3
    int np = nt * 16 + (L & 15);                   // n' in [0,4096)
    int g  = np & 3, j = np >> 2;
    int n  = g * 1024 + j;                         // original gate row
    int k0 = kc * 32 + (L >> 4) * 8;               // k in [0,2048)
    const float* src = (k0 < 1024)
        ? (Wih + ((size_t)l * 4096 + n) * 1024 + k0)
        : (Whh + ((size_t)l * 4096 + n) * 1024 + (k0 - 1024));
    float4 s0 = *(const float4*)(src);
    float4 s1 = *(const float4*)(src + 4);
    float sv[8] = {s0.x, s0.y, s0.z, s0.w, s1.x, s1.y, s1.z, s1.w};
    unsigned short hb[8], lb[8];
#pragma unroll
    for (int e = 0; e < 8; ++e) split_bf16(sv[e], hb[e], lb[e]);
    size_t dst = (((size_t)l * 64 + kc) * 256 + nt) * 512 + (size_t)L * 8;
    *(ushort4*)&Whi[dst]     = make_ushort4(hb[0], hb[1], hb[2], hb[3]);
    *(ushort4*)&Whi[dst + 4] = make_ushort4(hb[4], hb[5], hb[6], hb[7]);
    *(ushort4*)&Wlo[dst]     = make_ushort4(lb[0], lb[1], lb[2], lb[3]);
    *(ushort4*)&Wlo[dst + 4] = make_ushort4(lb[4], lb[5], lb[6], lb[7]);
}

// ---------------------------------------------------------------------------
// prep_state2: states (A-swizzled hi/lo), combined bias (gate-interleaved),
// transposed c (cT[l][j*64+b]) so the epilogue's c access is coalesced.
// ---------------------------------------------------------------------------
__global__ __launch_bounds__(256)
void prep_state2(const float* __restrict__ x, const float* __restrict__ h0,
                 const float* __restrict__ c0,
                 const float* __restrict__ bih, const float* __restrict__ bhh,
                 unsigned short* __restrict__ Xhi, unsigned short* __restrict__ Xlo,
                 unsigned short* __restrict__ Hhi, unsigned short* __restrict__ Hlo,
                 float* __restrict__ cT, float* __restrict__ bc)
{
    int gid = blockIdx.x * 256 + threadIdx.x;
    if (gid < 5 * 65536) {
        int buf = gid >> 16;             // 0 = x, 1..4 = layer buf-1
        int e = gid & 65535;
        int b = e >> 10, jg = e & 1023;
        float v = (buf == 0) ? x[e] : h0[(size_t)(buf - 1) * 65536 + e];
        size_t idx = aswz(b, jg);
        unsigned short hh, hl; split_bf16(v, hh, hl);
        if (buf == 0) { Xhi[idx] = hh; Xlo[idx] = hl; }
        else {
            Hhi[(size_t)(buf - 1) * 65536 + idx] = hh;
            Hlo[(size_t)(buf - 1) * 65536 + idx] = hl;
        }
    } else if (gid < 5 * 65536 + 16384) {
        int idx = gid - 5 * 65536;       // (l, n')
        int l = idx >> 12, np = idx & 4095;
        int g = np & 3, j = np >> 2;
        bc[l * 4096 + np] = bih[l * 4096 + g * 1024 + j] + bhh[l * 4096 + g * 1024 + j];
    } else if (gid < 5 * 65536 + 16384 + 4 * 65536) {
        int idx = gid - (5 * 65536 + 16384);
        int l = idx >> 16, e = idx & 65535;
        int b = e & 63, j = e >> 6;
        cT[(size_t)l * 65536 + j * 64 + b] = c0[(size_t)l * 65536 + b * 1024 + j];
    }
}

// ---------------------------------------------------------------------------
// lstm_fused: the whole T x L loop in ONE cooperative kernel.
// grid = 256 blocks (one N'=16 tile each) x 768 threads = 12 waves
//   = 4 M-quarters x 3 split segments (s0: hi*hi, s1: lo*hi, s2: hi*lo).
// K-loop: 32 phases of 2 kc; B staged via 4-deep register ring (vmcnt(3)
// latency tolerance), A prefetched 2 phases ahead, 2 accumulators.
// Barrier = raw lgkmcnt(0)+s_barrier: global prefetches stay in flight.
// ---------------------------------------------------------------------------
#define CELL_BAR() asm volatile("s_waitcnt lgkmcnt(0)\n\ts_barrier" ::: "memory")

__global__ __launch_bounds__(768, 1)
void lstm_fused(const unsigned short* __restrict__ Whi, const unsigned short* __restrict__ Wlo,
                const unsigned short* __restrict__ Xhi, const unsigned short* __restrict__ Xlo,
                unsigned short* __restrict__ Hhi, unsigned short* __restrict__ Hlo,
                float* __restrict__ cT, const float* __restrict__ bc,
                float* __restrict__ out)
{
    cg::grid_group grid = cg::this_grid();
    __shared__ __align__(16) unsigned short Bs[2][2][2][512];  // [buf][kcl][part][512]: 8 KB
    __shared__ __align__(16) float Gs[3840];                   // 12 tiles x 16 rows x 20 (pad)

    const int tid = threadIdx.x;
    const int L = tid & 63;
    const int w = tid >> 6;          // 0..11
    const int q = w & 3;             // M-quarter
    const int s = w >> 2;            // split segment 0..2
    const int bj = blockIdx.x;       // n'-tile
    const bool stager = (w < 4);     // waves 0..3 stage B
    const int kpar  = w & 1;         // stager: kc parity within phase
    const int spart = (w >> 1) & 1;  // stager: 0=hi, 1=lo
    const int bpart = (s == 2) ? 1 : 0;
    const size_t alane = (size_t)q * 512 + (size_t)L * 8;
    const size_t blane = (size_t)L * 8;

    for (int t = 0; t < NT; ++t) {
        const int pr = t & 1, pw = pr ^ 1;
        for (int l = 0; l < NL; ++l) {
            // ---- per-cell pointer selection ----
            const unsigned short *aI_hi, *aI_lo;
            if (l == 0) {
                if (t == 0) { aI_hi = Xhi; aI_lo = Xlo; }
                else        { aI_hi = Hhi + HOFF(pr, 3); aI_lo = Hlo + HOFF(pr, 3); }
            } else          { aI_hi = Hhi + HOFF(pw, l - 1); aI_lo = Hlo + HOFF(pw, l - 1); }
            const unsigned short* AIs = (s == 1) ? aI_lo : aI_hi;               // k < 1024
            const unsigned short* ARs = (s == 1) ? (Hlo + HOFF(pr, l))          // k >= 1024
                                                 : (Hhi + HOFF(pr, l));
            const unsigned short* wsrc = (spart ? Wlo : Whi) + (size_t)l * 8388608;

            f32x4 acc0 = {0.f, 0.f, 0.f, 0.f};
            f32x4 acc1 = {0.f, 0.f, 0.f, 0.f};

#define BSTG(f) (*(const uint4*)(wsrc + (size_t)((2 * (f) + kpar) * 256 + bj) * 512 + blane))
#define ALOAD(kc_) (*(const bf16x8*)((((kc_) < 32) ? AIs : ARs) + ((size_t)((kc_) & 31)) * 2048 + alane))

            // ---- prologue: ring <- phases 0..3; A pairs for phases 0,1 ----
            uint4 br0, br1, br2, br3;
            if (stager) { br0 = BSTG(0); br1 = BSTG(1); br2 = BSTG(2); br3 = BSTG(3); }
            bf16x8 a00 = ALOAD(0), a01 = ALOAD(1);   // phase 0
            bf16x8 a10 = ALOAD(2), a11 = ALOAD(3);   // phase 1
            if (stager) *(uint4*)(&Bs[0][kpar][spart][L * 8]) = br0;
            CELL_BAR();

            // ---- 32 phases of 2 kc ----
#define PHASE_BODY(J, JP, JN, BRJ, BRN, AX0, AX1, p)                               \
            do {                                                                   \
                const int pj = (p) + (J);                                          \
                if (stager && pj + 4 < 32) BRJ = BSTG(pj + 4);                     \
                {                                                                  \
                    bf16x8 bf0 = *(const bf16x8*)(&Bs[JP][0][bpart][L * 8]);       \
                    bf16x8 bf1 = *(const bf16x8*)(&Bs[JP][1][bpart][L * 8]);       \
                    acc0 = __builtin_amdgcn_mfma_f32_16x16x32_bf16(AX0, bf0, acc0, 0, 0, 0); \
                    acc1 = __builtin_amdgcn_mfma_f32_16x16x32_bf16(AX1, bf1, acc1, 0, 0, 0); \
                }                                                                  \
                if (pj + 2 < 32) { AX0 = ALOAD(2 * (pj + 2)); AX1 = ALOAD(2 * (pj + 2) + 1); } \
                if (stager && pj + 1 < 32)                                         \
                    *(uint4*)(&Bs[JP ^ 1][kpar][spart][L * 8]) = BRN;              \
                CELL_BAR();                                                        \
            } while (0)

#pragma unroll
            for (int p = 0; p < 32; p += 4) {
                PHASE_BODY(0, 0, 1, br0, br1, a00, a01, p);
                PHASE_BODY(1, 1, 2, br1, br2, a10, a11, p);
                PHASE_BODY(2, 0, 3, br2, br3, a00, a01, p);
                PHASE_BODY(3, 1, 0, br3, br0, a10, a11, p);
            }
#undef PHASE_BODY
#undef BSTG
#undef ALOAD

            // ---- scatter segment accumulators to padded Gs ----
            {
                f32x4 av = acc0 + acc1;
                const int mq = L >> 4, nl = L & 15;
                float* gw = &Gs[(size_t)((s * 4 + q) * 16) * 20 + nl];
#pragma unroll
                for (int r = 0; r < 4; ++r) gw[(mq * 4 + r) * 20] = av[r];
            }
            __syncthreads();

            // ---- epilogue: 64 threads, one batch row each, 4 h-dims ----
            if (tid < 64) {
                const int bl = tid;
                const int qq = bl >> 4, ml = bl & 15;
                const float* bc_l = bc + l * 4096 + bj * 16;
                float* cT_l = cT + (size_t)l * 65536;
                unsigned short* Hw_hi = Hhi + HOFF(pw, l);
                unsigned short* Hw_lo = Hlo + HOFF(pw, l);
                ushort4 h_hi, h_lo;
                float hv[4];
#pragma unroll
                for (int jl = 0; jl < 4; ++jl) {
                    const int base0 = (qq * 16 + ml) * 20 + jl * 4;
                    float4 g0 = *(const float4*)&Gs[base0];
                    float4 g1 = *(const float4*)&Gs[base0 + 1280];
                    float4 g2 = *(const float4*)&Gs[base0 + 2560];
                    float4 bb = *(const float4*)&bc_l[jl * 4];
                    float gi = g0.x + g1.x + g2.x + bb.x;
                    float gf = g0.y + g1.y + g2.y + bb.y;
                    float gg = g0.z + g1.z + g2.z + bb.z;
                    float go = g0.w + g1.w + g2.w + bb.w;
                    float si = 1.f / (1.f + __expf(-gi));
                    float sf = 1.f / (1.f + __expf(-gf));
                    float so = 1.f / (1.f + __expf(-go));
                    float tg = 1.f - 2.f / (__expf(2.f * gg) + 1.f);
                    const int jg = bj * 4 + jl;
                    float cold = cT_l[jg * 64 + bl];
                    float cn = sf * cold + si * tg;
                    cT_l[jg * 64 + bl] = cn;
                    float tc = 1.f - 2.f / (__expf(2.f * cn) + 1.f);
                    hv[jl] = so * tc;
                    unsigned short hh, hl; split_bf16(hv[jl], hh, hl);
                    ((unsigned short*)&h_hi)[jl] = hh;
                    ((unsigned short*)&h_lo)[jl] = hl;
                }
                size_t hidx = aswz(bl, bj * 4);
                *(ushort4*)&Hw_hi[hidx] = h_hi;
                *(ushort4*)&Hw_lo[hidx] = h_lo;
                if (l == 3)
                    *(float4*)&out[(size_t)bl * (NT * NH) + (size_t)t * NH + bj * 4]
                        = make_float4(hv[0], hv[1], hv[2], hv[3]);
            }
            grid.sync();
        }
    }
}

// ---------------------------------------------------------------------------
extern "C" void kernel_launch(void* const* d_in, const int* in_sizes, int n_in,
                              void* d_out, int out_size, void* d_ws, size_t ws_size,
                              hipStream_t stream)
{
    const float* x   = (const float*)d_in[0];
    const float* h0  = (const float*)d_in[1];
    const float* c0  = (const float*)d_in[2];
    const float* Wih = (const float*)d_in[3];
    const float* Whh = (const float*)d_in[4];
    const float* bih = (const float*)d_in[5];
    const float* bhh = (const float*)d_in[6];
    float* out = (float*)d_out;

    char* ws = (char*)d_ws;
    size_t off = 0;
    auto alloc = [&](size_t bytes) -> char* {
        char* p = ws + off; off += (bytes + 255) & ~(size_t)255; return p;
    };
    unsigned short* Whi = (unsigned short*)alloc((size_t)4 * 64 * 256 * 512 * 2);
    unsigned short* Wlo = (unsigned short*)alloc((size_t)4 * 64 * 256 * 512 * 2);
    unsigned short* Xhi = (unsigned short*)alloc(65536 * 2);
    unsigned short* Xlo = (unsigned short*)alloc(65536 * 2);
    unsigned short* Hhi = (unsigned short*)alloc((size_t)2 * 4 * 65536 * 2);
    unsigned short* Hlo = (unsigned short*)alloc((size_t)2 * 4 * 65536 * 2);
    float* cT = (float*)alloc((size_t)4 * 65536 * 4);
    float* bc = (float*)alloc((size_t)4 * 4096 * 4);

    prep_w<<<16384, 256, 0, stream>>>(Wih, Whh, Whi, Wlo);
    {
        int total = 5 * 65536 + 16384 + 4 * 65536;
        prep_state2<<<(total + 255) / 256, 256, 0, stream>>>(
            x, h0, c0, bih, bhh, Xhi, Xlo, Hhi, Hlo, cT, bc);
    }

    void* kargs[] = { (void*)&Whi, (void*)&Wlo, (void*)&Xhi, (void*)&Xlo,
                      (void*)&Hhi, (void*)&Hlo, (void*)&cT, (void*)&bc, (void*)&out };
    hipLaunchCooperativeKernel((void*)lstm_fused, dim3(256), dim3(768), kargs, 0, stream);

    (void)in_sizes; (void)n_in; (void)out_size; (void)ws_size;
}

// Round 3
// 13683.043 us; speedup vs baseline: 1.5543x; 1.5543x over previous
//
#include <hip/hip_runtime.h>
#include <hip/hip_bf16.h>
#include <stdint.h>

// Problem constants (fixed by the reference): B=64, L=4, H=1024, T=128.
#define NB   64
#define NH   1024
#define NL   4
#define NT   128

using bf16x8 = __attribute__((ext_vector_type(8))) short;  // 8 bf16 in 4 VGPRs
using f32x4  = __attribute__((ext_vector_type(4))) float;

// Split fp32 v into hi+lo bf16 (RNE). v ~= hi + lo with residual ~2^-17 * |v|.
__device__ __forceinline__ void split_bf16(float v, unsigned short& hi, unsigned short& lo) {
    unsigned u = __float_as_uint(v);
    unsigned short h = (unsigned short)((u + 0x7FFFu + ((u >> 16) & 1u)) >> 16);
    float hf = __uint_as_float((unsigned)h << 16);
    float r  = v - hf;
    unsigned ur = __float_as_uint(r);
    unsigned short l = (unsigned short)((ur + 0x7FFFu + ((ur >> 16) & 1u)) >> 16);
    hi = h; lo = l;
}

// A-swizzle for a (64 x 1024) activation: element (m,k) at
// ((k>>5)*4 + (m>>4))*512 + ((m&15) + ((k>>3)&3)*16)*8 + (k&7).   [verified R1/R2]
__device__ __forceinline__ size_t aswz(int m, int k) {
    return ((size_t)((k >> 5) * 4 + (m >> 4)) * 64 + ((m & 15) + ((k >> 3) & 3) * 16)) * 8
           + (k & 7);
}

#define HOFF(p, l) (((size_t)(p) * 4 + (l)) * 65536)

// ---------------------------------------------------------------------------
// prep_w: fp32 W_ih/W_hh -> ONE swizzled hi+lo bf16 stream, laid out so each
// block reads a fully sequential 128 KB per cell:
//   Wcat[l][bj][phase(16)][tile(4)][part(2: hi,lo)][512]
// tile = 2*kh + (kcl&1), phase = kcl>>1, kh = kc>=32, kcl = kc&31.
// Fragment content per (kc,bj): lane L holds W-as-B[k=kc*32+(L>>4)*8+j][n'] with
// n' = bj*16 + (L&15), n' = j*4 + g gate interleave.  [verified R1/R2]
// ---------------------------------------------------------------------------
__global__ __launch_bounds__(256)
void prep_w(const float* __restrict__ Wih, const float* __restrict__ Whh,
            unsigned short* __restrict__ Wcat)
{
    int gid = blockIdx.x * 256 + threadIdx.x;      // (l, kc, nt, L)
    int L  = gid & 63;
    int nt = (gid >> 6) & 255;
    int kc = (gid >> 14) & 63;
    int l  = gid >> 20;                            // 0..3
    int np = nt * 16 + (L & 15);                   // n' in [0,4096)
    int g  = np & 3, j = np >> 2;
    int n  = g * 1024 + j;                         // original gate row
    int k0 = kc * 32 + (L >> 4) * 8;               // k in [0,2048)
    const float* src = (k0 < 1024)
        ? (Wih + ((size_t)l * 4096 + n) * 1024 + k0)
        : (Whh + ((size_t)l * 4096 + n) * 1024 + (k0 - 1024));
    float4 s0 = *(const float4*)(src);
    float4 s1 = *(const float4*)(src + 4);
    float sv[8] = {s0.x, s0.y, s0.z, s0.w, s1.x, s1.y, s1.z, s1.w};
    unsigned short hb[8], lb[8];
#pragma unroll
    for (int e = 0; e < 8; ++e) split_bf16(sv[e], hb[e], lb[e]);
    int kh = kc >> 5, kcl = kc & 31;
    int pph = kcl >> 1, tile = 2 * kh + (kcl & 1);
    size_t slotbase = ((size_t)(l * 256 + nt) * 16 + pph) * 4096;
    size_t dsthi = slotbase + (size_t)tile * 1024 + (size_t)L * 8;
    *(ushort4*)&Wcat[dsthi]       = make_ushort4(hb[0], hb[1], hb[2], hb[3]);
    *(ushort4*)&Wcat[dsthi + 4]   = make_ushort4(hb[4], hb[5], hb[6], hb[7]);
    *(ushort4*)&Wcat[dsthi + 512] = make_ushort4(lb[0], lb[1], lb[2], lb[3]);
    *(ushort4*)&Wcat[dsthi + 516] = make_ushort4(lb[4], lb[5], lb[6], lb[7]);
}

// ---------------------------------------------------------------------------
// prep_state: x -> Xhi/Xlo (A-swizzle), h0 -> H(parity0) hi/lo (A-swizzle).
// ---------------------------------------------------------------------------
__global__ __launch_bounds__(256)
void prep_state(const float* __restrict__ x, const float* __restrict__ h0,
                unsigned short* __restrict__ Xhi, unsigned short* __restrict__ Xlo,
                unsigned short* __restrict__ Hhi, unsigned short* __restrict__ Hlo)
{
    int gid = blockIdx.x * 256 + threadIdx.x;
    if (gid >= 5 * 65536) return;
    int buf = gid >> 16;             // 0 = x, 1..4 = layer buf-1
    int e = gid & 65535;
    int b = e >> 10, jg = e & 1023;
    float v = (buf == 0) ? x[e] : h0[(size_t)(buf - 1) * 65536 + e];
    size_t idx = aswz(b, jg);
    unsigned short hh, hl; split_bf16(v, hh, hl);
    if (buf == 0) { Xhi[idx] = hh; Xlo[idx] = hl; }
    else {
        Hhi[(size_t)(buf - 1) * 65536 + idx] = hh;
        Hlo[(size_t)(buf - 1) * 65536 + idx] = hl;
    }
}

// ---------------------------------------------------------------------------
// lstm_fused: all 512 cells, one cooperative kernel, custom light barrier.
// 256 blocks (one N'=16 tile each) x 512 threads = 8 waves
//   = 4 M-quarters (q) x 2 K-halves (kh: 0 = layer input, 1 = recurrent h).
// Per wave per kc: 3 MFMAs (Ahi·Bhi, Alo·Bhi, Ahi·Blo) on 3 acc chains.
// 16 phases x 2 kc; B staged LDS (2 slots) via 4-deep register ring;
// lgkm-only phase barrier keeps global prefetches in flight.
// ---------------------------------------------------------------------------
#define CELL_BAR() asm volatile("s_waitcnt lgkmcnt(0)\n\ts_barrier" ::: "memory")

__global__ __launch_bounds__(512, 2)
void lstm_fused(const unsigned short* __restrict__ Wcat,
                const unsigned short* __restrict__ Xhi, const unsigned short* __restrict__ Xlo,
                unsigned short* __restrict__ Hhi, unsigned short* __restrict__ Hlo,
                const float* __restrict__ c0,
                const float* __restrict__ bih, const float* __restrict__ bhh,
                float* __restrict__ out, unsigned* __restrict__ sync)
{
    __shared__ __align__(16) unsigned short Bls[2][4096];  // 2 slots x 8 KB
    __shared__ __align__(16) float Gs[2560];               // 8 tiles x 16 x 20 (pad)
    __shared__ __align__(16) float4 cLd[4][64];            // c state: [l][batch], block-private
    __shared__ float bcs[64];                              // combined bias [l][16 n'-local]

    const int tid = threadIdx.x;
    const int L = tid & 63;
    const int w = tid >> 6;          // 0..7
    const int q = w & 3;             // M-quarter (batch rows q*16..)
    const int kh = w >> 2;           // K-half: 0 = input (k<1024), 1 = recurrent
    const int bj = blockIdx.x;       // n'-tile
    const size_t alane = (size_t)q * 512 + (size_t)L * 8;
    unsigned* cnt  = sync;
    unsigned* flag = sync + 32;

    // ---- one-time init: bias + c into LDS ----
    if (tid < 64) {
        int li = tid >> 4, i = tid & 15;
        int jj = bj * 4 + (i >> 2), g = i & 3;
        bcs[tid] = bih[li * 4096 + g * 1024 + jj] + bhh[li * 4096 + g * 1024 + jj];
    }
    if (tid < 64) {
#pragma unroll
        for (int li = 0; li < 4; ++li) {
            const float* cs = c0 + (size_t)li * 65536 + (size_t)tid * 1024 + bj * 4;
            cLd[li][tid] = make_float4(cs[0], cs[1], cs[2], cs[3]);
        }
    }

    // ---- prologue staging prefetch for cell 0 (layer 0) ----
    uint4 br[4];
    {
        const unsigned short* wb0 = Wcat + (size_t)bj * 65536;  // l=0
#pragma unroll
        for (int jp = 0; jp < 4; ++jp)
            br[jp] = *(const uint4*)(wb0 + (size_t)jp * 4096 + (size_t)tid * 8);
    }

    for (int u = 0; u < NT * NL; ++u) {
        const int t = u >> 2, l = u & 3;
        const int pr = t & 1, pw = pr ^ 1;

        // ---- grid barrier (custom, monotonic) ----
        if (u) {
            if (tid == 0) {
                unsigned old = __hip_atomic_fetch_add(cnt, 1u, __ATOMIC_ACQ_REL,
                                                      __HIP_MEMORY_SCOPE_AGENT);
                if (old == 256u * (unsigned)u - 1u) {
                    __hip_atomic_store(flag, (unsigned)u, __ATOMIC_RELEASE,
                                       __HIP_MEMORY_SCOPE_AGENT);
                } else {
                    while (__hip_atomic_load(flag, __ATOMIC_RELAXED,
                                             __HIP_MEMORY_SCOPE_AGENT) < (unsigned)u)
                        __builtin_amdgcn_s_sleep(2);
                    (void)__hip_atomic_load(flag, __ATOMIC_ACQUIRE,
                                            __HIP_MEMORY_SCOPE_AGENT);
                }
            }
            __syncthreads();
        }

        // ---- per-cell pointers ----
        const unsigned short *AIh, *AIl;
        if (l == 0) {
            if (t == 0) { AIh = Xhi; AIl = Xlo; }
            else        { AIh = Hhi + HOFF(pr, 3); AIl = Hlo + HOFF(pr, 3); }
        } else          { AIh = Hhi + HOFF(pw, l - 1); AIl = Hlo + HOFF(pw, l - 1); }
        const unsigned short* Ah = kh ? (Hhi + HOFF(pr, l)) : AIh;
        const unsigned short* Al = kh ? (Hlo + HOFF(pr, l)) : AIl;
        const unsigned short* wbase = Wcat + ((size_t)l * 256 + bj) * 65536;

        // ---- cell prologue: slot0 <- phase0; A sets for phases 0,1 ----
        *(uint4*)(&Bls[0][(size_t)tid * 8]) = br[0];
        bf16x8 av[2][4];
#pragma unroll
        for (int s = 0; s < 2; ++s) {
            const int kc0 = 2 * s;
            av[s][0] = *(const bf16x8*)(Ah + (size_t)kc0 * 2048 + alane);
            av[s][1] = *(const bf16x8*)(Al + (size_t)kc0 * 2048 + alane);
            av[s][2] = *(const bf16x8*)(Ah + (size_t)(kc0 + 1) * 2048 + alane);
            av[s][3] = *(const bf16x8*)(Al + (size_t)(kc0 + 1) * 2048 + alane);
        }
        CELL_BAR();

        f32x4 acc_h0 = {0.f, 0.f, 0.f, 0.f};
        f32x4 acc_h1 = {0.f, 0.f, 0.f, 0.f};
        f32x4 acc_l  = {0.f, 0.f, 0.f, 0.f};

        // ---- 16 phases of 2 kc ----
#pragma unroll
        for (int p = 0; p < 16; ++p) {
            const int sl = p & 1;
            if (p + 4 < 16)
                br[p & 3] = *(const uint4*)(wbase + (size_t)(p + 4) * 4096 + (size_t)tid * 8);
            bf16x8 bh0 = *(const bf16x8*)(&Bls[sl][(2 * kh + 0) * 1024 +   0 + L * 8]);
            bf16x8 bl0 = *(const bf16x8*)(&Bls[sl][(2 * kh + 0) * 1024 + 512 + L * 8]);
            bf16x8 bh1 = *(const bf16x8*)(&Bls[sl][(2 * kh + 1) * 1024 +   0 + L * 8]);
            bf16x8 bl1 = *(const bf16x8*)(&Bls[sl][(2 * kh + 1) * 1024 + 512 + L * 8]);
            acc_h0 = __builtin_amdgcn_mfma_f32_16x16x32_bf16(av[sl][0], bh0, acc_h0, 0, 0, 0);
            acc_h0 = __builtin_amdgcn_mfma_f32_16x16x32_bf16(av[sl][1], bh0, acc_h0, 0, 0, 0);
            acc_h1 = __builtin_amdgcn_mfma_f32_16x16x32_bf16(av[sl][2], bh1, acc_h1, 0, 0, 0);
            acc_h1 = __builtin_amdgcn_mfma_f32_16x16x32_bf16(av[sl][3], bh1, acc_h1, 0, 0, 0);
            acc_l  = __builtin_amdgcn_mfma_f32_16x16x32_bf16(av[sl][0], bl0, acc_l,  0, 0, 0);
            acc_l  = __builtin_amdgcn_mfma_f32_16x16x32_bf16(av[sl][2], bl1, acc_l,  0, 0, 0);
            if (p + 2 < 16) {
                const int kc0 = 2 * (p + 2);
                av[sl][0] = *(const bf16x8*)(Ah + (size_t)kc0 * 2048 + alane);
                av[sl][1] = *(const bf16x8*)(Al + (size_t)kc0 * 2048 + alane);
                av[sl][2] = *(const bf16x8*)(Ah + (size_t)(kc0 + 1) * 2048 + alane);
                av[sl][3] = *(const bf16x8*)(Al + (size_t)(kc0 + 1) * 2048 + alane);
            }
            if (p + 1 < 16)
                *(uint4*)(&Bls[sl ^ 1][(size_t)tid * 8]) = br[(p + 1) & 3];
            CELL_BAR();
        }

        // ---- scatter partials: tile tw = kh*4+q; lane holds D[mq*4+r][nl] ----
        {
            f32x4 avv = (acc_h0 + acc_h1) + acc_l;
            const int mq = L >> 4, nl = L & 15;
            float* gw = &Gs[(kh * 4 + q) * 320 + nl];
#pragma unroll
            for (int r = 0; r < 4; ++r) gw[(mq * 4 + r) * 20] = avv[r];
        }
        __syncthreads();

        // ---- epilogue: 64 threads, one batch row each, 4 h-dims ----
        if (tid < 64) {
            const int bl = tid, qq = bl >> 4, ml = bl & 15;
            float4 cv = cLd[l][bl];
            float ca[4] = {cv.x, cv.y, cv.z, cv.w};
            float hv[4];
            ushort4 h_hi, h_lo;
#pragma unroll
            for (int jl = 0; jl < 4; ++jl) {
                const int base0 = (qq * 16 + ml) * 20 + jl * 4;
                float4 g0 = *(const float4*)&Gs[base0];
                float4 g1 = *(const float4*)&Gs[base0 + 1280];
                float4 bb = *(const float4*)&bcs[l * 16 + jl * 4];
                float gi = g0.x + g1.x + bb.x;
                float gf = g0.y + g1.y + bb.y;
                float gg = g0.z + g1.z + bb.z;
                float go = g0.w + g1.w + bb.w;
                float si = 1.f / (1.f + __expf(-gi));
                float sf = 1.f / (1.f + __expf(-gf));
                float so = 1.f / (1.f + __expf(-go));
                float tg = 1.f - 2.f / (__expf(2.f * gg) + 1.f);
                float cn = sf * ca[jl] + si * tg;
                ca[jl] = cn;
                float tc = 1.f - 2.f / (__expf(2.f * cn) + 1.f);
                hv[jl] = so * tc;
                unsigned short hh, hl; split_bf16(hv[jl], hh, hl);
                ((unsigned short*)&h_hi)[jl] = hh;
                ((unsigned short*)&h_lo)[jl] = hl;
            }
            cLd[l][bl] = make_float4(ca[0], ca[1], ca[2], ca[3]);
            size_t hidx = aswz(bl, bj * 4);
            union { ushort4 v; unsigned long long u; } ch, cl2;
            ch.v = h_hi; cl2.v = h_lo;
            __hip_atomic_store((unsigned long long*)(Hhi + HOFF(pw, l) + hidx), ch.u,
                               __ATOMIC_RELAXED, __HIP_MEMORY_SCOPE_AGENT);
            __hip_atomic_store((unsigned long long*)(Hlo + HOFF(pw, l) + hidx), cl2.u,
                               __ATOMIC_RELAXED, __HIP_MEMORY_SCOPE_AGENT);
            if (l == 3)
                *(float4*)&out[(size_t)bl * (NT * NH) + (size_t)t * NH + bj * 4]
                    = make_float4(hv[0], hv[1], hv[2], hv[3]);
        }
        __syncthreads();   // all lanes' agent stores drained (vmcnt0) before arrive

        // ---- cross-barrier staging prefetch for next cell ----
        if (u + 1 < NT * NL) {
            const int ln = (u + 1) & 3;
            const unsigned short* wbn = Wcat + ((size_t)ln * 256 + bj) * 65536;
#pragma unroll
            for (int jp = 0; jp < 4; ++jp)
                br[jp] = *(const uint4*)(wbn + (size_t)jp * 4096 + (size_t)tid * 8);
        }
    }
}

// ---------------------------------------------------------------------------
extern "C" void kernel_launch(void* const* d_in, const int* in_sizes, int n_in,
                              void* d_out, int out_size, void* d_ws, size_t ws_size,
                              hipStream_t stream)
{
    const float* x   = (const float*)d_in[0];
    const float* h0  = (const float*)d_in[1];
    const float* c0  = (const float*)d_in[2];
    const float* Wih = (const float*)d_in[3];
    const float* Whh = (const float*)d_in[4];
    const float* bih = (const float*)d_in[5];
    const float* bhh = (const float*)d_in[6];
    float* out = (float*)d_out;

    char* ws = (char*)d_ws;
    size_t off = 0;
    auto alloc = [&](size_t bytes) -> char* {
        char* p = ws + off; off += (bytes + 255) & ~(size_t)255; return p;
    };
    unsigned short* Wcat = (unsigned short*)alloc((size_t)4 * 256 * 65536 * 2);  // 128 MiB
    unsigned short* Xhi  = (unsigned short*)alloc(65536 * 2);
    unsigned short* Xlo  = (unsigned short*)alloc(65536 * 2);
    unsigned short* Hhi  = (unsigned short*)alloc((size_t)2 * 4 * 65536 * 2);
    unsigned short* Hlo  = (unsigned short*)alloc((size_t)2 * 4 * 65536 * 2);
    unsigned*       sync = (unsigned*)alloc(256);

    hipMemsetAsync(sync, 0, 256, stream);
    prep_w<<<16384, 256, 0, stream>>>(Wih, Whh, Wcat);
    prep_state<<<1280, 256, 0, stream>>>(x, h0, Xhi, Xlo, Hhi, Hlo);

    void* kargs[] = { (void*)&Wcat, (void*)&Xhi, (void*)&Xlo, (void*)&Hhi, (void*)&Hlo,
                      (void*)&c0, (void*)&bih, (void*)&bhh, (void*)&out, (void*)&sync };
    hipLaunchCooperativeKernel((void*)lstm_fused, dim3(256), dim3(512), kargs, 0, stream);

    (void)in_sizes; (void)n_in; (void)out_size; (void)ws_size;
}

// Round 4
// 9327.982 us; speedup vs baseline: 2.2799x; 1.4669x over previous
//
#include <hip/hip_runtime.h>
#include <hip/hip_bf16.h>
#include <stdint.h>

// Problem constants (fixed by the reference): B=64, L=4, H=1024, T=128.
#define NB   64
#define NH   1024
#define NL   4
#define NT   128

using bf16x8 = __attribute__((ext_vector_type(8))) short;  // 8 bf16 in 4 VGPRs
using f32x4  = __attribute__((ext_vector_type(4))) float;

// Split fp32 v into hi+lo bf16 (RNE). v ~= hi + lo with residual ~2^-17 * |v|.
__device__ __forceinline__ void split_bf16(float v, unsigned short& hi, unsigned short& lo) {
    unsigned u = __float_as_uint(v);
    unsigned short h = (unsigned short)((u + 0x7FFFu + ((u >> 16) & 1u)) >> 16);
    float hf = __uint_as_float((unsigned)h << 16);
    float r  = v - hf;
    unsigned ur = __float_as_uint(r);
    unsigned short l = (unsigned short)((ur + 0x7FFFu + ((ur >> 16) & 1u)) >> 16);
    hi = h; lo = l;
}

// A-swizzle for a (64 x 1024) activation: element (m,k) at
// ((k>>5)*4 + (m>>4))*512 + ((m&15) + ((k>>3)&3)*16)*8 + (k&7).   [verified R1-R3]
__device__ __forceinline__ size_t aswz(int m, int k) {
    return ((size_t)((k >> 5) * 4 + (m >> 4)) * 64 + ((m & 15) + ((k >> 3) & 3) * 16)) * 8
           + (k & 7);
}

#define HOFF(p, l) (((size_t)(p) * 4 + (l)) * 65536)

// global -> LDS direct copy, 16B per lane. lds base must be wave-uniform;
// HW scatters lane i at ldsbase + i*16.  [guide §5, m97]
__device__ __forceinline__ void gl2lds16(const void* g, void* l) {
    __builtin_amdgcn_global_load_lds(
        (const __attribute__((address_space(1))) unsigned int*)g,
        (__attribute__((address_space(3))) unsigned int*)l, 16, 0, 0);
}

// ---------------------------------------------------------------------------
// prep_w (VERBATIM R3): fp32 W -> swizzled hi/lo bf16 stream.
// Wcat[l][bj][phase 16][tile 4][part 2][512]; tile = 2*kh + (kcl&1),
// phase = kcl>>1. Per-cell-per-block stream = 16 phases x 8 KB, sequential.
// ---------------------------------------------------------------------------
__global__ __launch_bounds__(256)
void prep_w(const float* __restrict__ Wih, const float* __restrict__ Whh,
            unsigned short* __restrict__ Wcat)
{
    int gid = blockIdx.x * 256 + threadIdx.x;      // (l, kc, nt, L)
    int L  = gid & 63;
    int nt = (gid >> 6) & 255;
    int kc = (gid >> 14) & 63;
    int l  = gid >> 20;                            // 0..3
    int np = nt * 16 + (L & 15);                   // n' in [0,4096)
    int g  = np & 3, j = np >> 2;
    int n  = g * 1024 + j;                         // original gate row
    int k0 = kc * 32 + (L >> 4) * 8;               // k in [0,2048)
    const float* src = (k0 < 1024)
        ? (Wih + ((size_t)l * 4096 + n) * 1024 + k0)
        : (Whh + ((size_t)l * 4096 + n) * 1024 + (k0 - 1024));
    float4 s0 = *(const float4*)(src);
    float4 s1 = *(const float4*)(src + 4);
    float sv[8] = {s0.x, s0.y, s0.z, s0.w, s1.x, s1.y, s1.z, s1.w};
    unsigned short hb[8], lb[8];
#pragma unroll
    for (int e = 0; e < 8; ++e) split_bf16(sv[e], hb[e], lb[e]);
    int kh = kc >> 5, kcl = kc & 31;
    int pph = kcl >> 1, tile = 2 * kh + (kcl & 1);
    size_t slotbase = ((size_t)(l * 256 + nt) * 16 + pph) * 4096;
    size_t dsthi = slotbase + (size_t)tile * 1024 + (size_t)L * 8;
    *(ushort4*)&Wcat[dsthi]       = make_ushort4(hb[0], hb[1], hb[2], hb[3]);
    *(ushort4*)&Wcat[dsthi + 4]   = make_ushort4(hb[4], hb[5], hb[6], hb[7]);
    *(ushort4*)&Wcat[dsthi + 512] = make_ushort4(lb[0], lb[1], lb[2], lb[3]);
    *(ushort4*)&Wcat[dsthi + 516] = make_ushort4(lb[4], lb[5], lb[6], lb[7]);
}

// ---------------------------------------------------------------------------
// prep_state (VERBATIM R3)
// ---------------------------------------------------------------------------
__global__ __launch_bounds__(256)
void prep_state(const float* __restrict__ x, const float* __restrict__ h0,
                unsigned short* __restrict__ Xhi, unsigned short* __restrict__ Xlo,
                unsigned short* __restrict__ Hhi, unsigned short* __restrict__ Hlo)
{
    int gid = blockIdx.x * 256 + threadIdx.x;
    if (gid >= 5 * 65536) return;
    int buf = gid >> 16;
    int e = gid & 65535;
    int b = e >> 10, jg = e & 1023;
    float v = (buf == 0) ? x[e] : h0[(size_t)(buf - 1) * 65536 + e];
    size_t idx = aswz(b, jg);
    unsigned short hh, hl; split_bf16(v, hh, hl);
    if (buf == 0) { Xhi[idx] = hh; Xlo[idx] = hl; }
    else {
        Hhi[(size_t)(buf - 1) * 65536 + idx] = hh;
        Hlo[(size_t)(buf - 1) * 65536 + idx] = hl;
    }
}

// ---------------------------------------------------------------------------
// lstm_fused: 512 cells, one persistent kernel, custom grid barrier.
// 256 blocks x 512 thr (8 waves = 4 M-quarters x 2 K-halves).
// B: global_load_lds into a 6-slot x 8KB LDS ring, issue distance 5.
// A: named 4-set register ring (constant indices only -> no scratch).
// Phase barrier: s_waitcnt vmcnt(14) + s_barrier (prefetches stay in flight).
// ---------------------------------------------------------------------------
#define WRAP6(x) ((x) >= 6 ? (x) - 6 : (x))

#define AISSUE(AV, pp) do {                                                   \
    const unsigned short* _ab = Ah + (size_t)(pp) * 4096 + alane;             \
    const unsigned short* _lb = Al + (size_t)(pp) * 4096 + alane;             \
    AV[0] = *(const bf16x8*)(_ab);                                            \
    AV[1] = *(const bf16x8*)(_lb);                                            \
    AV[2] = *(const bf16x8*)(_ab + 2048);                                     \
    AV[3] = *(const bf16x8*)(_lb + 2048);                                     \
} while (0)

#define PHASE(p, AV_C, AV_N) do {                                             \
    asm volatile("s_waitcnt vmcnt(14)\n\ts_barrier" ::: "memory");            \
    const int sp_ = WRAP6(cb + ((p) % 6));                                    \
    const unsigned short* bs_ = &Bls[sp_ * 4096 + kh * 2048];                 \
    bf16x8 bh0 = *(const bf16x8*)(bs_ +    0 + L * 8);                        \
    bf16x8 bl0 = *(const bf16x8*)(bs_ +  512 + L * 8);                        \
    bf16x8 bh1 = *(const bf16x8*)(bs_ + 1024 + L * 8);                        \
    bf16x8 bl1 = *(const bf16x8*)(bs_ + 1536 + L * 8);                        \
    acc0 = __builtin_amdgcn_mfma_f32_16x16x32_bf16(AV_C[0], bh0, acc0, 0, 0, 0); \
    acc1 = __builtin_amdgcn_mfma_f32_16x16x32_bf16(AV_C[1], bh0, acc1, 0, 0, 0); \
    acc2 = __builtin_amdgcn_mfma_f32_16x16x32_bf16(AV_C[0], bl0, acc2, 0, 0, 0); \
    acc0 = __builtin_amdgcn_mfma_f32_16x16x32_bf16(AV_C[2], bh1, acc0, 0, 0, 0); \
    acc1 = __builtin_amdgcn_mfma_f32_16x16x32_bf16(AV_C[3], bh1, acc1, 0, 0, 0); \
    acc2 = __builtin_amdgcn_mfma_f32_16x16x32_bf16(AV_C[2], bl1, acc2, 0, 0, 0); \
    AISSUE(AV_N, ((p) + 3) & 15);                                             \
    { const int si_ = WRAP6(cb + (((p) + 5) % 6));                            \
      const unsigned short* gsrc_ = ((p) < 11)                                \
          ? (wsrc + ((p) + 5) * 4096) : (wnext + ((p) - 11) * 4096);          \
      gl2lds16(gsrc_ + (size_t)w * 512 + (size_t)L * 8,                       \
               &Bls[si_ * 4096 + w * 512]); }                                 \
} while (0)

__global__ __launch_bounds__(512, 2)
void lstm_fused(const unsigned short* __restrict__ Wcat,
                const unsigned short* __restrict__ Xhi, const unsigned short* __restrict__ Xlo,
                unsigned short* __restrict__ Hhi, unsigned short* __restrict__ Hlo,
                const float* __restrict__ c0,
                const float* __restrict__ bih, const float* __restrict__ bhh,
                float* __restrict__ out, unsigned* __restrict__ sync)
{
    __shared__ __align__(16) unsigned short Bls[6 * 4096];   // 48 KB, 6x8KB ring
    __shared__ __align__(16) float Gs[2560];                 // 8 tiles x 16 x 20 (pad)
    __shared__ __align__(16) float4 cLd[4][64];              // c state (block-private)
    __shared__ float bcs[64];                                // combined bias

    const int tid = threadIdx.x;
    const int L = tid & 63;
    const int w = tid >> 6;          // 0..7
    const int q = w & 3;             // M-quarter
    const int kh = w >> 2;           // K-half: 0 = input, 1 = recurrent
    const int bj = blockIdx.x;       // n'-tile
    const size_t alane = (size_t)q * 512 + (size_t)L * 8;
    unsigned* cnt  = sync;
    unsigned* flag = sync + 32;

    // ---- one-time init: bias + c into LDS (wave0 only; wave0 consumes) ----
    if (tid < 64) {
        int li = tid >> 4, i = tid & 15;
        int jj = bj * 4 + (i >> 2), g = i & 3;
        bcs[tid] = bih[li * 4096 + g * 1024 + jj] + bhh[li * 4096 + g * 1024 + jj];
#pragma unroll
        for (int li2 = 0; li2 < 4; ++li2) {
            const float* cs = c0 + (size_t)li2 * 65536 + (size_t)tid * 1024 + bj * 4;
            cLd[li2][tid] = make_float4(cs[0], cs[1], cs[2], cs[3]);
        }
    }

    bf16x8 av0[4], av1[4], av2[4], av3[4];
    const unsigned short *Ah, *Al, *wsrc, *wnext;
    int cb = 0;

    // ---- pre-loop prologue: cell 0 pointers, slots 0..4, A sets 0..2 ----
    {
        Ah = kh ? (Hhi + HOFF(0, 0)) : Xhi;
        Al = kh ? (Hlo + HOFF(0, 0)) : Xlo;
        wsrc  = Wcat + (size_t)bj * 65536;            // l=0
        wnext = Wcat + ((size_t)1 * 256 + bj) * 65536;
#pragma unroll
        for (int g = 0; g < 5; ++g)
            gl2lds16(wsrc + (size_t)g * 4096 + (size_t)w * 512 + (size_t)L * 8,
                     &Bls[g * 4096 + w * 512]);
        AISSUE(av0, 0); AISSUE(av1, 1); AISSUE(av2, 2);
        asm volatile("s_waitcnt vmcnt(0)" ::: "memory");
    }

#pragma unroll 1
    for (int u = 0; u < NT * NL; ++u) {
        const int t = u >> 2, l = u & 3;
        const int pr = t & 1, pw = pr ^ 1;

        // ---- grid barrier (R3-verified protocol) ----
        if (u) {
            if (tid == 0) {
                unsigned old = __hip_atomic_fetch_add(cnt, 1u, __ATOMIC_ACQ_REL,
                                                      __HIP_MEMORY_SCOPE_AGENT);
                if (old == 256u * (unsigned)u - 1u) {
                    __hip_atomic_store(flag, (unsigned)u, __ATOMIC_RELEASE,
                                       __HIP_MEMORY_SCOPE_AGENT);
                } else {
                    while (__hip_atomic_load(flag, __ATOMIC_RELAXED,
                                             __HIP_MEMORY_SCOPE_AGENT) < (unsigned)u)
                        __builtin_amdgcn_s_sleep(2);
                    (void)__hip_atomic_load(flag, __ATOMIC_ACQUIRE,
                                            __HIP_MEMORY_SCOPE_AGENT);
                }
            }
            asm volatile("s_barrier" ::: "memory");
        }

        // ---- per-cell pointers ----
        {
            const unsigned short *AIh, *AIl;
            if (l == 0) {
                if (t == 0) { AIh = Xhi; AIl = Xlo; }
                else        { AIh = Hhi + HOFF(pr, 3); AIl = Hlo + HOFF(pr, 3); }
            } else          { AIh = Hhi + HOFF(pw, l - 1); AIl = Hlo + HOFF(pw, l - 1); }
            Ah = kh ? (Hhi + HOFF(pr, l)) : AIh;
            Al = kh ? (Hlo + HOFF(pr, l)) : AIl;
            wsrc  = Wcat + ((size_t)l * 256 + bj) * 65536;
            wnext = Wcat + ((size_t)((l + 1) & 3) * 256 + bj) * 65536;
        }
        if (u) { AISSUE(av0, 0); AISSUE(av1, 1); AISSUE(av2, 2); }

        f32x4 acc0 = {0.f, 0.f, 0.f, 0.f};
        f32x4 acc1 = {0.f, 0.f, 0.f, 0.f};
        f32x4 acc2 = {0.f, 0.f, 0.f, 0.f};

        PHASE( 0, av0, av3);  PHASE( 1, av1, av0);  PHASE( 2, av2, av1);
        PHASE( 3, av3, av2);  PHASE( 4, av0, av3);  PHASE( 5, av1, av0);
        PHASE( 6, av2, av1);  PHASE( 7, av3, av2);  PHASE( 8, av0, av3);
        PHASE( 9, av1, av0);  PHASE(10, av2, av1);  PHASE(11, av3, av2);
        PHASE(12, av0, av3);  PHASE(13, av1, av0);  PHASE(14, av2, av1);
        PHASE(15, av3, av2);

        // ---- scatter partials: tile = kh*4+q; lane holds D[mq*4+r][nl] ----
        {
            f32x4 avv = (acc0 + acc1) + acc2;
            const int mq = L >> 4, nl = L & 15;
            float* gw = &Gs[(kh * 4 + q) * 320 + nl];
#pragma unroll
            for (int r = 0; r < 4; ++r) gw[(mq * 4 + r) * 20] = avv[r];
        }
        asm volatile("s_waitcnt lgkmcnt(0)\n\ts_barrier" ::: "memory");

        // ---- epilogue: wave0, one batch row each, 4 h-dims (R3-verified) ----
        if (tid < 64) {
            const int bl = tid, qq = bl >> 4, ml = bl & 15;
            float4 cv = cLd[l][bl];
            float ca[4] = {cv.x, cv.y, cv.z, cv.w};
            float hv[4];
            ushort4 h_hi, h_lo;
#pragma unroll
            for (int jl = 0; jl < 4; ++jl) {
                const int base0 = (qq * 16 + ml) * 20 + jl * 4;
                float4 g0 = *(const float4*)&Gs[base0];
                float4 g1 = *(const float4*)&Gs[base0 + 1280];
                float4 bb = *(const float4*)&bcs[l * 16 + jl * 4];
                float gi = g0.x + g1.x + bb.x;
                float gf = g0.y + g1.y + bb.y;
                float gg = g0.z + g1.z + bb.z;
                float go = g0.w + g1.w + bb.w;
                float si = 1.f / (1.f + __expf(-gi));
                float sf = 1.f / (1.f + __expf(-gf));
                float so = 1.f / (1.f + __expf(-go));
                float tg = 1.f - 2.f / (__expf(2.f * gg) + 1.f);
                float cn = sf * ca[jl] + si * tg;
                ca[jl] = cn;
                float tc = 1.f - 2.f / (__expf(2.f * cn) + 1.f);
                hv[jl] = so * tc;
                unsigned short hh, hl; split_bf16(hv[jl], hh, hl);
                ((unsigned short*)&h_hi)[jl] = hh;
                ((unsigned short*)&h_lo)[jl] = hl;
            }
            cLd[l][bl] = make_float4(ca[0], ca[1], ca[2], ca[3]);
            size_t hidx = aswz(bl, bj * 4);
            union { ushort4 v; unsigned long long u; } ch, cl2;
            ch.v = h_hi; cl2.v = h_lo;
            __hip_atomic_store((unsigned long long*)(Hhi + HOFF(pw, l) + hidx), ch.u,
                               __ATOMIC_RELAXED, __HIP_MEMORY_SCOPE_AGENT);
            __hip_atomic_store((unsigned long long*)(Hlo + HOFF(pw, l) + hidx), cl2.u,
                               __ATOMIC_RELAXED, __HIP_MEMORY_SCOPE_AGENT);
            if (l == 3)
                *(float4*)&out[(size_t)bl * (NT * NH) + (size_t)t * NH + bj * 4]
                    = make_float4(hv[0], hv[1], hv[2], hv[3]);
        }

        cb += 4; if (cb >= 6) cb -= 6;
    }
}

// ---------------------------------------------------------------------------
extern "C" void kernel_launch(void* const* d_in, const int* in_sizes, int n_in,
                              void* d_out, int out_size, void* d_ws, size_t ws_size,
                              hipStream_t stream)
{
    const float* x   = (const float*)d_in[0];
    const float* h0  = (const float*)d_in[1];
    const float* c0  = (const float*)d_in[2];
    const float* Wih = (const float*)d_in[3];
    const float* Whh = (const float*)d_in[4];
    const float* bih = (const float*)d_in[5];
    const float* bhh = (const float*)d_in[6];
    float* out = (float*)d_out;

    char* ws = (char*)d_ws;
    size_t off = 0;
    auto alloc = [&](size_t bytes) -> char* {
        char* p = ws + off; off += (bytes + 255) & ~(size_t)255; return p;
    };
    unsigned short* Wcat = (unsigned short*)alloc((size_t)4 * 256 * 65536 * 2);  // 128 MiB
    unsigned short* Xhi  = (unsigned short*)alloc(65536 * 2);
    unsigned short* Xlo  = (unsigned short*)alloc(65536 * 2);
    unsigned short* Hhi  = (unsigned short*)alloc((size_t)2 * 4 * 65536 * 2);
    unsigned short* Hlo  = (unsigned short*)alloc((size_t)2 * 4 * 65536 * 2);
    unsigned*       sync = (unsigned*)alloc(256);

    hipMemsetAsync(sync, 0, 256, stream);
    prep_w<<<16384, 256, 0, stream>>>(Wih, Whh, Wcat);
    prep_state<<<1280, 256, 0, stream>>>(x, h0, Xhi, Xlo, Hhi, Hlo);

    void* kargs[] = { (void*)&Wcat, (void*)&Xhi, (void*)&Xlo, (void*)&Hhi, (void*)&Hlo,
                      (void*)&c0, (void*)&bih, (void*)&bhh, (void*)&out, (void*)&sync };
    hipLaunchCooperativeKernel((void*)lstm_fused, dim3(256), dim3(512), kargs, 0, stream);

    (void)in_sizes; (void)n_in; (void)out_size; (void)ws_size;
}